// Round 7
// baseline (746.110 us; speedup 1.0000x reference)
//
#include <hip/hip_runtime.h>
#include <stdint.h>

typedef unsigned short u16;
typedef short v8s __attribute__((ext_vector_type(8)));
typedef float v4f __attribute__((ext_vector_type(4)));

typedef __attribute__((address_space(1))) uint32_t g_u32;
typedef __attribute__((address_space(3))) uint32_t l_u32;

__device__ __forceinline__ void glds16(const void* g, void* l) {
    __builtin_amdgcn_global_load_lds((const g_u32*)g, (l_u32*)l, 16, 0, 0);
}
__device__ __forceinline__ u16 f2b(float f) {
    uint32_t u = __builtin_bit_cast(uint32_t, f);
    u += 0x7FFFu + ((u >> 16) & 1u);
    return (u16)(u >> 16);
}
__device__ __forceinline__ uint32_t pk2(float a, float b) {
    uint32_t ua = __builtin_bit_cast(uint32_t, a) + 0x8000u;
    uint32_t ub = __builtin_bit_cast(uint32_t, b) + 0x8000u;
    return __builtin_amdgcn_perm(ub, ua, 0x07060302u);
}

#define MTOT  32768
#define HDIM  768
#define KDIM  2000
#define KPAD  2016

#define VMW(n) asm volatile("s_waitcnt vmcnt(" #n ")" ::: "memory")
#define BARX do { __builtin_amdgcn_s_barrier(); __builtin_amdgcn_sched_barrier(0); } while (0)

// ---------------- K0: weights -> bf16 (proj_w padded K 2000->2016 with zeros) -----------
__global__ __launch_bounds__(256) void cvt_weights(
    const float* __restrict__ pw, const float* __restrict__ nw,
    u16* __restrict__ Wb, u16* __restrict__ NWb)
{
    const int h = blockIdx.x;  // 768
    const float* src = pw + (size_t)h * KDIM;
    u16* dst = Wb + (size_t)h * KPAD;
    for (int k = threadIdx.x; k < KPAD; k += 256)
        dst[k] = (k < KDIM) ? f2b(src[k]) : (u16)0;
    const float* s2 = nw + (size_t)h * HDIM;
    u16* d2 = NWb + (size_t)h * HDIM;
    for (int k = threadIdx.x; k < HDIM; k += 256)
        d2[k] = f2b(s2[k]);
}

// ---------------- K0b: compact rows with negs==1 ----------------------------------------
// cmap[c] = orig row of compact row c (padded with 0 up to MTOT); pos[orig] = compact idx.
__global__ __launch_bounds__(256) void compact_k(
    const int* __restrict__ negs, int* __restrict__ cmap,
    int* __restrict__ pos, int* __restrict__ cnt)
{
    __shared__ int pref[257];
    const int t = threadIdx.x;
    const int base = t * 128;
    int c = 0;
    for (int j = 0; j < 128; j++) c += (negs[base + j] == 1);
    __shared__ int wsum[256];
    wsum[t] = c;
    __syncthreads();
    if (t == 0) {
        int a = 0;
        for (int i = 0; i < 256; i++) { pref[i] = a; a += wsum[i]; }
        pref[256] = a;
        cnt[0] = a;
    }
    __syncthreads();
    int off = pref[t];
    for (int j = 0; j < 128; j++) {
        const int r = base + j;
        if (negs[r] == 1) { cmap[off] = r; pos[r] = off; off++; }
    }
    const int total = pref[256];
    for (int j = total + t; j < MTOT; j += 256) cmap[j] = 0;
}

// ---------------- K1: GEMM1  128x256 tile, BK=32, 8 waves, 2 blocks/CU ------------------
// Wave = 64x64 out, acc[4][4] = 64 AGPR; total live ~90 VGPR -> NO SPILL (R4-R6 lesson:
// reg-staging + big acc blew the 256 budget; here staging is pure global_load_lds).
// A staged fp32 via glds (bank-swizzled, R0-proven), converted bf16 at fragment read.
// 2-slot LDS (64 KB), counted vmcnt: 4 glds/wave/slot, VMW(4) at top, issue(kb+2)
// after the post-compute barrier. Tail k>=2000: A clamped, Wb zero-padded -> 0.
__global__ __launch_bounds__(512, 4) void gemm1(
    const float* __restrict__ A, const u16* __restrict__ Wb,
    const float* __restrict__ pb,
    const int* __restrict__ i_ty, const int* __restrict__ i_la,
    const int* __restrict__ i_op, const int* __restrict__ i_in, const int* __restrict__ i_ou,
    const float* __restrict__ te, const float* __restrict__ le, const float* __restrict__ oe,
    const float* __restrict__ ie, const float* __restrict__ ooe,
    u16* __restrict__ Xb)
{
    __shared__ __align__(16) float Asf[2][128 * 32];  // 2 x 16 KB fp32
    __shared__ __align__(16) u16  Bs[2][256 * 32];    // 2 x 16 KB bf16 (64 KB total)

    // XCD swizzle: 768 % 8 == 0; the 3 n-tiles of one m-panel stay on one XCD
    const int bid = blockIdx.x;
    const int sw = (bid & 7) * 96 + (bid >> 3);
    const int mt = sw / 3, nt = sw % 3;
    const int m_base = mt * 128, n_base = nt * 256;

    const int tid = threadIdx.x;
    const int w = tid >> 6, lane = tid & 63;
    const int lm = lane & 15, quad = lane >> 4;
    const int wm = (w >> 2) * 64, wn = (w & 3) * 64;

    // A staging: wave w covers rows [w*16, w*16+16), 2 glds (8 rows each).
    // LDS 16B slot s of row rl holds global chunk s^(rl&7).
    const float* aRowBase[2];
    int aOff[2], aBase[2];
#pragma unroll
    for (int t = 0; t < 2; t++) {
        const int rl = w * 16 + t * 8 + (lane >> 3);
        aRowBase[t] = A + (size_t)(m_base + rl) * KDIM;
        aOff[t] = ((lane & 7) ^ (rl & 7)) * 4;
        aBase[t] = (w * 16 + t * 8) * 32;
    }
    // B staging: wave w covers rows [w*32, w*32+32), 2 glds (16 rows each).
    const u16* bSrc[2];
    int bBase[2];
#pragma unroll
    for (int t = 0; t < 2; t++) {
        const int rl = w * 32 + t * 16 + (lane >> 2);
        const int c = (lane & 3) ^ ((rl >> 1) & 3);
        bSrc[t] = Wb + (size_t)(n_base + rl) * KPAD + c * 8;
        bBase[t] = (w * 32 + t * 16) * 32;
    }

    v4f acc[4][4];
#pragma unroll
    for (int i = 0; i < 4; i++)
#pragma unroll
        for (int j = 0; j < 4; j++) acc[i][j] = (v4f){0.f, 0.f, 0.f, 0.f};

    auto issue = [&](int kb) {
        const int sl = kb & 1;
#pragma unroll
        for (int t = 0; t < 2; t++) {
            int k = kb * 32 + aOff[t];
            k = (k > 1996) ? 1996 : k;           // tail: garbage * zero-padded Wb
            glds16(aRowBase[t] + k, &Asf[sl][aBase[t]]);
        }
#pragma unroll
        for (int t = 0; t < 2; t++)
            glds16(bSrc[t] + kb * 32, &Bs[sl][bBase[t]]);
    };
    auto compute = [&](int kb) {
        const int sl = kb & 1;
        v8s af[4], bf[4];
#pragma unroll
        for (int i = 0; i < 4; i++) {
            const int r = wm + i * 16 + lm;
            const int s8 = r & 7;
            const float4 lo = *(const float4*)&Asf[sl][r * 32 + (((2 * quad)     ^ s8) << 2)];
            const float4 hi = *(const float4*)&Asf[sl][r * 32 + (((2 * quad + 1) ^ s8) << 2)];
            int4 p;
            p.x = (int)pk2(lo.x, lo.y); p.y = (int)pk2(lo.z, lo.w);
            p.z = (int)pk2(hi.x, hi.y); p.w = (int)pk2(hi.z, hi.w);
            af[i] = __builtin_bit_cast(v8s, p);
        }
#pragma unroll
        for (int j = 0; j < 4; j++) {
            const int r = wn + j * 16 + lm;
            bf[j] = *(const v8s*)&Bs[sl][r * 32 + ((quad ^ ((r >> 1) & 3)) << 3)];
        }
#pragma unroll
        for (int i = 0; i < 4; i++)
#pragma unroll
            for (int j = 0; j < 4; j++)
                acc[i][j] = __builtin_amdgcn_mfma_f32_16x16x32_bf16(af[i], bf[j], acc[i][j], 0, 0, 0);
    };

    issue(0);
    issue(1);                                   // 8 outstanding

    for (int kb = 0; kb < 61; ++kb) {
        VMW(4);                                  // own slot-kb glds done
        BARX;                                    // everyone's slot-kb done
        compute(kb);
        __builtin_amdgcn_sched_barrier(0);
        BARX;                                    // all reads of slot kb complete
        issue(kb + 2);                           // overwrite slot kb&1 (safe)
    }
    VMW(4); BARX; compute(61);
    __builtin_amdgcn_sched_barrier(0);
    BARX;
    VMW(0); BARX; compute(62);

    // epilogue: + proj_b + 5 table gathers, write bf16 x
#pragma unroll
    for (int i = 0; i < 4; i++) {
#pragma unroll
        for (int r = 0; r < 4; r++) {
            const int row = m_base + wm + i * 16 + quad * 4 + r;
            const int ty = i_ty[row], la = i_la[row], op = i_op[row];
            const int di = i_in[row], doo = i_ou[row];
            const float* pte = te + (size_t)ty * HDIM;
            const float* ple = le + (size_t)la * HDIM;
            const float* poe = oe + (size_t)op * HDIM;
            const float* pie = ie + (size_t)di * HDIM;
            const float* pou = ooe + (size_t)doo * HDIM;
            u16* orow = Xb + (size_t)row * HDIM;
#pragma unroll
            for (int j = 0; j < 4; j++) {
                const int col = n_base + wn + j * 16 + lm;
                float v = acc[i][j][r] + pb[col] + pte[col] + ple[col] + poe[col] + pie[col] + pou[col];
                orow[col] = f2b(v);
            }
        }
    }
}

// ---------------- K2: GEMM2 over COMPACTED rows (negs==1 only, ~50% of work) ------------
// Same template, all-bf16 glds; A rows gathered via cmap. Fixed worst-case grid,
// blocks with m_base >= cnt exit uniformly. Padded cmap rows (=0) compute garbage
// into Yb[c >= cnt], never read. 3 glds/wave/slot -> VMW(3).
__global__ __launch_bounds__(512, 4) void gemm2(
    const u16* __restrict__ Xb, const u16* __restrict__ NWb,
    const float* __restrict__ nb, const int* __restrict__ cmap,
    const int* __restrict__ cnt, u16* __restrict__ Yb)
{
    __shared__ __align__(16) u16 As[2][128 * 32];  // 2 x 8 KB
    __shared__ __align__(16) u16 Bs[2][256 * 32];  // 2 x 16 KB (48 KB total)

    const int bid = blockIdx.x;
    const int sw = (bid & 7) * 96 + (bid >> 3);
    const int mt = sw / 3, nt = sw % 3;
    const int m_base = mt * 128, n_base = nt * 256;
    if (m_base >= cnt[0]) return;

    const int tid = threadIdx.x;
    const int w = tid >> 6, lane = tid & 63;
    const int lm = lane & 15, quad = lane >> 4;
    const int wm = (w >> 2) * 64, wn = (w & 3) * 64;

    // A: 1 glds/wave (16 rows), rows gathered through cmap
    const int rlA = w * 16 + (lane >> 2);
    const int cAx = (lane & 3) ^ ((rlA >> 1) & 3);
    const u16* aSrc = Xb + (size_t)cmap[m_base + rlA] * HDIM + cAx * 8;
    const int aBase = (w * 16) * 32;
    // B: 2 glds/wave
    const u16* bSrc[2];
    int bBase[2];
#pragma unroll
    for (int t = 0; t < 2; t++) {
        const int rl = w * 32 + t * 16 + (lane >> 2);
        const int c = (lane & 3) ^ ((rl >> 1) & 3);
        bSrc[t] = NWb + (size_t)(n_base + rl) * HDIM + c * 8;
        bBase[t] = (w * 32 + t * 16) * 32;
    }

    v4f acc[4][4];
#pragma unroll
    for (int i = 0; i < 4; i++)
#pragma unroll
        for (int j = 0; j < 4; j++) acc[i][j] = (v4f){0.f, 0.f, 0.f, 0.f};

    auto issue = [&](int kb) {
        const int sl = kb & 1;
        glds16(aSrc + kb * 32, &As[sl][aBase]);
#pragma unroll
        for (int t = 0; t < 2; t++)
            glds16(bSrc[t] + kb * 32, &Bs[sl][bBase[t]]);
    };
    auto compute = [&](int kb) {
        const int sl = kb & 1;
        v8s af[4], bf[4];
#pragma unroll
        for (int i = 0; i < 4; i++) {
            const int r = wm + i * 16 + lm;
            af[i] = *(const v8s*)&As[sl][r * 32 + ((quad ^ ((r >> 1) & 3)) << 3)];
        }
#pragma unroll
        for (int j = 0; j < 4; j++) {
            const int r = wn + j * 16 + lm;
            bf[j] = *(const v8s*)&Bs[sl][r * 32 + ((quad ^ ((r >> 1) & 3)) << 3)];
        }
#pragma unroll
        for (int i = 0; i < 4; i++)
#pragma unroll
            for (int j = 0; j < 4; j++)
                acc[i][j] = __builtin_amdgcn_mfma_f32_16x16x32_bf16(af[i], bf[j], acc[i][j], 0, 0, 0);
    };

    issue(0);
    issue(1);                                   // 6 outstanding

    for (int kb = 0; kb < 22; ++kb) {           // 24 K-steps
        VMW(3);
        BARX;
        compute(kb);
        __builtin_amdgcn_sched_barrier(0);
        BARX;
        issue(kb + 2);
    }
    VMW(3); BARX; compute(22);
    __builtin_amdgcn_sched_barrier(0);
    BARX;
    VMW(0); BARX; compute(23);

#pragma unroll
    for (int i = 0; i < 4; i++) {
#pragma unroll
        for (int r = 0; r < 4; r++) {
            const int crow = m_base + wm + i * 16 + quad * 4 + r;  // compact row index
            u16* orow = Yb + (size_t)crow * HDIM;
#pragma unroll
            for (int j = 0; j < 4; j++) {
                const int col = n_base + wn + j * 16 + lm;
                orow[col] = f2b(acc[i][j][r] + nb[col]);
            }
        }
    }
}

// ---------------- K3: select (negs, via pos map) + LayerNorm, one wave per row ----------
__global__ __launch_bounds__(256) void ln_k(
    const u16* __restrict__ Xb, const u16* __restrict__ Yb,
    const int* __restrict__ negs, const int* __restrict__ pos,
    const float* __restrict__ g, const float* __restrict__ b,
    float* __restrict__ out)
{
    const int w = threadIdx.x >> 6, lane = threadIdx.x & 63;
    const int row = blockIdx.x * 4 + w;
    const u16* src = (negs[row] == 1) ? (Yb + (size_t)pos[row] * HDIM)
                                      : (Xb + (size_t)row * HDIM);

    float v[12];
    float s = 0.f, ss = 0.f;
#pragma unroll
    for (int p = 0; p < 3; p++) {
        uint2 u = *(const uint2*)(src + (p * 64 + lane) * 4);
        float f0 = __builtin_bit_cast(float, u.x << 16);
        float f1 = __builtin_bit_cast(float, u.x & 0xFFFF0000u);
        float f2 = __builtin_bit_cast(float, u.y << 16);
        float f3 = __builtin_bit_cast(float, u.y & 0xFFFF0000u);
        v[p * 4 + 0] = f0; v[p * 4 + 1] = f1; v[p * 4 + 2] = f2; v[p * 4 + 3] = f3;
        s += f0 + f1 + f2 + f3;
        ss += f0 * f0 + f1 * f1 + f2 * f2 + f3 * f3;
    }
#pragma unroll
    for (int off = 1; off < 64; off <<= 1) {
        s += __shfl_xor(s, off);
        ss += __shfl_xor(ss, off);
    }
    const float mean = s * (1.f / (float)HDIM);
    const float var = ss * (1.f / (float)HDIM) - mean * mean;
    const float rs = rsqrtf(var + 1e-12f);

    float* orow = out + (size_t)row * HDIM;
#pragma unroll
    for (int p = 0; p < 3; p++) {
        const int c0 = (p * 64 + lane) * 4;
        float4 gg = *(const float4*)(g + c0);
        float4 bb = *(const float4*)(b + c0);
        float4 o;
        o.x = (v[p * 4 + 0] - mean) * rs * gg.x + bb.x;
        o.y = (v[p * 4 + 1] - mean) * rs * gg.y + bb.y;
        o.z = (v[p * 4 + 2] - mean) * rs * gg.z + bb.z;
        o.w = (v[p * 4 + 3] - mean) * rs * gg.w + bb.w;
        *(float4*)(orow + c0) = o;
    }
}

extern "C" void kernel_launch(void* const* d_in, const int* in_sizes, int n_in,
                              void* d_out, int out_size, void* d_ws, size_t ws_size,
                              hipStream_t stream) {
    (void)in_sizes; (void)n_in; (void)out_size; (void)ws_size;
    const float* A   = (const float*)d_in[0];
    const int* i_ty  = (const int*)d_in[1];
    const int* i_la  = (const int*)d_in[2];
    const int* i_op  = (const int*)d_in[3];
    const int* i_in  = (const int*)d_in[4];
    const int* i_ou  = (const int*)d_in[5];
    const int* negs  = (const int*)d_in[6];
    const float* te  = (const float*)d_in[7];
    const float* le  = (const float*)d_in[8];
    const float* oe  = (const float*)d_in[9];
    const float* ie  = (const float*)d_in[10];
    const float* ooe = (const float*)d_in[11];
    const float* pw  = (const float*)d_in[12];
    const float* pb  = (const float*)d_in[13];
    const float* nw  = (const float*)d_in[14];
    const float* nb  = (const float*)d_in[15];
    const float* lng = (const float*)d_in[16];
    const float* lnb = (const float*)d_in[17];
    float* out = (float*)d_out;

    // workspace layout (~100.3 MiB)
    char* ws = (char*)d_ws;
    u16* Wb  = (u16*)ws;                                    // 768*2016*2  = 3,096,576
    u16* NWb = (u16*)(ws + 3096576);                        // 768*768*2   = 1,179,648
    u16* Xb  = (u16*)(ws + 4276224);                        // 32768*768*2 = 50,331,648
    u16* Yb  = (u16*)(ws + 4276224 + 50331648);             // 50,331,648
    int* cmap = (int*)(ws + 4276224 + 100663296);           // 131,072
    int* pos  = (int*)(ws + 4276224 + 100663296 + 131072);  // 131,072
    int* cnt  = (int*)(ws + 4276224 + 100663296 + 262144);  // 128

    cvt_weights<<<768, 256, 0, stream>>>(pw, nw, Wb, NWb);
    compact_k<<<1, 256, 0, stream>>>(negs, cmap, pos, cnt);
    gemm1<<<768, 512, 0, stream>>>(A, Wb, pb, i_ty, i_la, i_op, i_in, i_ou,
                                   te, le, oe, ie, ooe, Xb);
    gemm2<<<768, 512, 0, stream>>>(Xb, NWb, nb, cmap, cnt, Yb);
    ln_k<<<8192, 256, 0, stream>>>(Xb, Yb, negs, pos, lng, lnb, out);
}